// Round 1
// baseline (494.266 us; speedup 1.0000x reference)
//
#include <hip/hip_runtime.h>
#include <math.h>

#define D 512
#define BATCH 256

typedef float f4 __attribute__((ext_vector_type(4)));

// ---------------- kernel 1: projections Y = X @ W^T (+ sigmoid/bias for o) ----
// X [256,512], W [512,512] row-major. BM=BN=64, BK=32, 256 threads, 4x4 micro.
// (unchanged from verified baseline — ~15-25 us, not the bottleneck this round)
__global__ __launch_bounds__(256) void proj_gemm(
    const float* __restrict__ X,
    const float* __restrict__ Wq, const float* __restrict__ Wk,
    const float* __restrict__ Wv, const float* __restrict__ Wo,
    const float* __restrict__ Wo_b,
    float* __restrict__ qb, float* __restrict__ kb,
    float* __restrict__ vb, float* __restrict__ ob)
{
    const int mat = blockIdx.z;
    const float* W = (mat == 0) ? Wq : (mat == 1) ? Wk : (mat == 2) ? Wv : Wo;
    float* Y = (mat == 0) ? qb : (mat == 1) ? kb : (mat == 2) ? vb : ob;

    const int m0 = blockIdx.y * 64;
    const int n0 = blockIdx.x * 64;

    __shared__ float Xs[64][33];
    __shared__ float Ws[64][33];

    const int t = threadIdx.x;
    const int lr = t >> 3;          // 0..31 (tile row for loading)
    const int lc = (t & 7) * 4;     // k offset 0,4,..,28
    const int ty = t >> 4;          // 0..15
    const int tx = t & 15;          // 0..15

    float acc[4][4] = {};

    for (int k0 = 0; k0 < D; k0 += 32) {
        float4 xa = *(const float4*)&X[(size_t)(m0 + lr) * D + k0 + lc];
        float4 xb = *(const float4*)&X[(size_t)(m0 + lr + 32) * D + k0 + lc];
        float4 wa = *(const float4*)&W[(size_t)(n0 + lr) * D + k0 + lc];
        float4 wb = *(const float4*)&W[(size_t)(n0 + lr + 32) * D + k0 + lc];
        __syncthreads();
        Xs[lr][lc + 0] = xa.x; Xs[lr][lc + 1] = xa.y; Xs[lr][lc + 2] = xa.z; Xs[lr][lc + 3] = xa.w;
        Xs[lr + 32][lc + 0] = xb.x; Xs[lr + 32][lc + 1] = xb.y; Xs[lr + 32][lc + 2] = xb.z; Xs[lr + 32][lc + 3] = xb.w;
        Ws[lr][lc + 0] = wa.x; Ws[lr][lc + 1] = wa.y; Ws[lr][lc + 2] = wa.z; Ws[lr][lc + 3] = wa.w;
        Ws[lr + 32][lc + 0] = wb.x; Ws[lr + 32][lc + 1] = wb.y; Ws[lr + 32][lc + 2] = wb.z; Ws[lr + 32][lc + 3] = wb.w;
        __syncthreads();
#pragma unroll
        for (int kk = 0; kk < 32; ++kk) {
            float a0 = Xs[ty * 4 + 0][kk];
            float a1 = Xs[ty * 4 + 1][kk];
            float a2 = Xs[ty * 4 + 2][kk];
            float a3 = Xs[ty * 4 + 3][kk];
            float b0 = Ws[tx * 4 + 0][kk];
            float b1 = Ws[tx * 4 + 1][kk];
            float b2 = Ws[tx * 4 + 2][kk];
            float b3 = Ws[tx * 4 + 3][kk];
            acc[0][0] += a0 * b0; acc[0][1] += a0 * b1; acc[0][2] += a0 * b2; acc[0][3] += a0 * b3;
            acc[1][0] += a1 * b0; acc[1][1] += a1 * b1; acc[1][2] += a1 * b2; acc[1][3] += a1 * b3;
            acc[2][0] += a2 * b0; acc[2][1] += a2 * b1; acc[2][2] += a2 * b2; acc[2][3] += a2 * b3;
            acc[3][0] += a3 * b0; acc[3][1] += a3 * b1; acc[3][2] += a3 * b2; acc[3][3] += a3 * b3;
        }
    }

#pragma unroll
    for (int i = 0; i < 4; ++i) {
        int row = m0 + ty * 4 + i;
#pragma unroll
        for (int j = 0; j < 4; ++j) {
            int col = n0 + tx * 4 + j;
            float y = acc[i][j];
            if (mat == 3) y = 1.0f / (1.0f + expf(-(y + Wo_b[col])));
            Y[(size_t)row * D + col] = y;
        }
    }
}

// ---------------- block reduce for 1024 threads (16 waves) -------------------
__device__ __forceinline__ float blockReduceSum16(float val, float* red) {
#pragma unroll
    for (int off = 32; off > 0; off >>= 1)
        val += __shfl_down(val, off, 64);
    const int lane = threadIdx.x & 63;
    const int w = threadIdx.x >> 6;
    __syncthreads();
    if (lane == 0) red[w] = val;
    __syncthreads();
    float s = 0.0f;
#pragma unroll
    for (int i = 0; i < 16; ++i) s += red[i];
    return s;
}

// ---------------- kernel 2: mega — gates + n_t + C update + retrieval + LN ---
// One block per batch element b. 1024 threads = 16 waves; each wave owns one
// C row at a time (rows 16j+w), fully coalesced 2x float4 RMW per row.
// k,q live in registers (loaded once, not once per row). C streams use
// non-temporal load/store (written-once / read-once data, don't pollute L2/L3).
__global__ __launch_bounds__(1024) void mega(
    const float* __restrict__ x, const float* __restrict__ n_prev,
    const float* __restrict__ C_prev,
    const float* __restrict__ wi_w, const float* __restrict__ wi_b,
    const float* __restrict__ wf_w, const float* __restrict__ wf_b,
    const float* __restrict__ qb, const float* __restrict__ kb,
    const float* __restrict__ vb, const float* __restrict__ ob,
    const float* __restrict__ ln_g, const float* __restrict__ ln_be,
    float* __restrict__ out_h, float* __restrict__ out_C,
    float* __restrict__ out_n)
{
    __shared__ float red[16];
    __shared__ float hs[D];

    const int b = blockIdx.x;
    const int t = threadIdx.x;
    const int lane = t & 63;
    const int w = t >> 6;           // wave id 0..15

    const size_t bD = (size_t)b * D;

    // ---- gates i_t, f_t (x . wi_w, x . wf_w) ----
    float si = 0.0f, sf = 0.0f;
    if (t < D) {
        float xv = x[bD + t];
        si = xv * wi_w[t];
        sf = xv * wf_w[t];
    }
    si = blockReduceSum16(si, red);
    sf = blockReduceSum16(sf, red);
    const float i_t = fminf(expf(si + wi_b[0]), 50.0f);
    const float f_t = 1.0f / (1.0f + expf(-(sf + wf_b[0])));

    // ---- n_t and nq ----
    float nq_p = 0.0f;
    if (t < D) {
        float nv = f_t * n_prev[bD + t] + i_t * kb[bD + t];
        out_n[bD + t] = nv;
        nq_p = nv * qb[bD + t];
    }
    const float nq = blockReduceSum16(nq_p, red);
    const float invnq = 1.0f / fmaxf(fabsf(nq), 1.0f);

    // ---- k, q resident in registers: lane holds elems [4*lane..] and [4*(lane+64)..]
    const f4* k4 = (const f4*)(kb + bD);
    const f4* q4 = (const f4*)(qb + bD);
    const f4 ka = k4[lane], kc = k4[lane + 64];
    const f4 qa = q4[lane], qc = q4[lane + 64];

    const float* vrow = vb + bD;
    const float* orow = ob + bD;
    const f4* Cp = (const f4*)(C_prev + bD * D);
    f4*       Ct = (f4*)(out_C + bD * D);

    // ---- C_t = f*C_prev + (i*v[r]) * k ; h~[r] = (C_t[r] . q) ----
#pragma unroll 2
    for (int j = 0; j < D / 16; ++j) {
        const int r = (j << 4) + w;                 // waves cover 16 consecutive rows
        const float a = i_t * vrow[r];
        const f4* cpr = Cp + (size_t)r * (D / 4);
        f4 c0 = __builtin_nontemporal_load(cpr + lane);
        f4 c1 = __builtin_nontemporal_load(cpr + lane + 64);
        f4 r0 = f_t * c0 + a * ka;
        f4 r1 = f_t * c1 + a * kc;
        f4* ctr = Ct + (size_t)r * (D / 4);
        __builtin_nontemporal_store(r0, ctr + lane);
        __builtin_nontemporal_store(r1, ctr + lane + 64);
        f4 m = r0 * qa + r1 * qc;
        float dot = m.x + m.y + m.z + m.w;
#pragma unroll
        for (int off = 32; off > 0; off >>= 1)
            dot += __shfl_down(dot, off, 64);
        if (lane == 0)
            hs[r] = dot * orow[r] * invnq;
    }

    // ---- LayerNorm epilogue (in-block; hs has all 512 values) ----
    __syncthreads();
    float h0 = (t < D) ? hs[t] : 0.0f;
    const float mu = blockReduceSum16(h0, red) * (1.0f / 512.0f);
    const float d0 = (t < D) ? (h0 - mu) : 0.0f;
    const float var = blockReduceSum16(d0 * d0, red) * (1.0f / 512.0f);
    const float rstd = rsqrtf(var + 1e-5f);
    if (t < D)
        out_h[bD + t] = d0 * rstd * ln_g[t] + ln_be[t];
}

// ---------------- launcher ----------------------------------------------------
extern "C" void kernel_launch(void* const* d_in, const int* in_sizes, int n_in,
                              void* d_out, int out_size, void* d_ws, size_t ws_size,
                              hipStream_t stream) {
    const float* x_t    = (const float*)d_in[0];
    const float* C_prev = (const float*)d_in[1];
    const float* n_prev = (const float*)d_in[2];
    const float* Wq     = (const float*)d_in[3];
    const float* Wk     = (const float*)d_in[4];
    const float* Wv     = (const float*)d_in[5];
    const float* wi_w   = (const float*)d_in[6];
    const float* wi_b   = (const float*)d_in[7];
    const float* wf_w   = (const float*)d_in[8];
    const float* wf_b   = (const float*)d_in[9];
    const float* Wo_w   = (const float*)d_in[10];
    const float* Wo_b   = (const float*)d_in[11];
    const float* ln_g   = (const float*)d_in[12];
    const float* ln_b   = (const float*)d_in[13];

    float* out = (float*)d_out;
    float* out_h = out;                                  // [256,512]
    float* out_C = out + (size_t)BATCH * D;              // [256,512,512]
    float* out_n = out + (size_t)BATCH * D + (size_t)BATCH * D * D; // [256,512]

    float* ws = (float*)d_ws;
    const size_t BD = (size_t)BATCH * D;                 // 131072
    float* qb = ws;
    float* kb = ws + BD;
    float* vb = ws + 2 * BD;
    float* ob = ws + 3 * BD;

    // 1) projections q,k,v,o (o fused with sigmoid+bias)
    proj_gemm<<<dim3(D / 64, BATCH / 64, 4), 256, 0, stream>>>(
        x_t, Wq, Wk, Wv, Wo_w, Wo_b, qb, kb, vb, ob);

    // 2) everything else, fused: gates + n_t + nq + C update + retrieval + LN
    mega<<<dim3(BATCH), 1024, 0, stream>>>(
        x_t, n_prev, C_prev, wi_w, wi_b, wf_w, wf_b,
        qb, kb, vb, ob, ln_g, ln_b, out_h, out_C, out_n);
}